// Round 6
// baseline (380.209 us; speedup 1.0000x reference)
//
#include <hip/hip_runtime.h>
#include <hip/hip_cooperative_groups.h>
#include <hip/hip_fp16.h>
#include <math.h>

namespace cg = cooperative_groups;

#define IN 8000
#define OC 10
#define NUNIT 1000              // 1000 units x 8 i
#define VACC_F (64 * OC * 16)   // 10240 floats
#define PART_H (64 * OC * 16)   // 10240 halfs per chunk (20 KB)

// per-unit f16 record: [8 il][10 o][16 d][8 e] (20480 B) then [8 il][64 b][8 e] (8192 B)
#define REC_B   28672
#define REC_H   14336
#define XOFF_B  20480
#define XOFF_H  10240
#define REC_TOTAL_B ((size_t)NUNIT * REC_B)   // 28,672,000

typedef __fp16 h2 __attribute__((ext_vector_type(2)));
typedef _Float16 half8 __attribute__((ext_vector_type(8)));
typedef float f32x16 __attribute__((ext_vector_type(16)));

__device__ __forceinline__ h2 asb(unsigned int v) { return __builtin_bit_cast(h2, v); }

__device__ __forceinline__ float dot2(h2 a, h2 b, float c) {
#if __has_builtin(__builtin_amdgcn_fdot2)
    return __builtin_amdgcn_fdot2(a, b, c, false);
#else
    return fmaf((float)a[0], (float)b[0], fmaf((float)a[1], (float)b[1], c));
#endif
}

__device__ __forceinline__ unsigned int pk_rn(float a, float b) {
    return __builtin_bit_cast(unsigned int, __float22half2_rn(make_float2(a, b)));
}

#define GLDS16(gp, lp) __builtin_amdgcn_global_load_lds(                      \
    (const __attribute__((address_space(1))) void*)(gp),                      \
    (__attribute__((address_space(3))) void*)(lp), 16, 0, 0)

// ---------------------------------------------------------------------------
// ONE persistent cooperative kernel: prep -> 3x (pass -> reduce), with
// grid.sync() between phases. Per-phase math/layouts are verbatim from the
// round-5 passing build (packed-f16 routing accumulator, max3 softmax,
// global_load_lds staging with the verified double-buffer + refill loop).
// Grid is runtime-sized to guaranteed co-residency (<= maxBlocks*256, cap
// 512); every block always owns unit `bid`, so all G part-chunks are valid.
// ---------------------------------------------------------------------------
__global__ __launch_bounds__(256, 2) void caps_fused(
    const float* __restrict__ W, const float* __restrict__ x,
    __fp16* __restrict__ rec, float* Vacc, __fp16* part,
    float* __restrict__ out)
{
    cg::grid_group gg = cg::this_grid();

    __shared__ __align__(16) unsigned char sm[2 * REC_B];   // 57344 B
    __shared__ __align__(16) unsigned char zs[16];          // zero slot
    __shared__ float redsm[4][16];                          // reduce-phase tmp

    const int t    = threadIdx.x;
    const int w    = t >> 6;
    const int lane = t & 63;
    const int lo   = lane & 31;
    const int hi   = lane >> 5;
    const int bt   = w & 1;            // b-half
    const int ph   = w >> 1;           // i-set half
    const int b    = bt * 32 + lo;
    const int bid  = blockIdx.x;
    const int G    = gridDim.x;
    const int d2   = t & 3;
    const int s4   = t >> 2;

    if (t < 4) ((unsigned int*)zs)[t] = 0u;

    // ---------------- phase 0: prep (f32 -> f16 unit records) ----------------
    // W granules: 1,280,000 x 8 halfs; d fastest -> 512 B contiguous per 16 thr.
    for (int g = bid * 256 + t; g < 1280000; g += G * 256) {
        int u  = g / 1280;
        int r  = g - u * 1280;
        int il = r / 160;
        int rr = r - il * 160;
        int o  = rr >> 4;
        int d  = rr & 15;
        const float* ip = W + ((size_t)o * IN + (size_t)(u * 8 + il)) * 128 + d * 8;
        float4 f0 = *(const float4*)(ip);
        float4 f1 = *(const float4*)(ip + 4);
        *(uint4*)(rec + (size_t)u * REC_H + il * 1280 + o * 128 + d * 8) =
            make_uint4(pk_rn(f0.x, f0.y), pk_rn(f0.z, f0.w),
                       pk_rn(f1.x, f1.y), pk_rn(f1.z, f1.w));
    }
    // x granules: 512,000 x 8 halfs; per-wave fixed i, b spans 0..63 ->
    // writes contiguous 1 KB (the pass's LDS row layout).
    for (int g = bid * 256 + t; g < 512000; g += G * 256) {
        int i  = g >> 6;
        int bb = g & 63;
        const float* ip = x + ((size_t)bb * IN + i) * 8;
        float4 f0 = *(const float4*)(ip);
        float4 f1 = *(const float4*)(ip + 4);
        *(uint4*)(rec + (size_t)(i >> 3) * REC_H + XOFF_H + (i & 7) * 512 + bb * 8) =
            make_uint4(pk_rn(f0.x, f0.y), pk_rn(f0.z, f0.w),
                       pk_rn(f1.x, f1.y), pk_rn(f1.z, f1.w));
    }
    gg.sync();

    // staging: 28 x 1 KiB chunks per unit; wave w issues q = c*4+w
    auto issue = [&](int st, int bufi) {
        const char* gp = (const char*)rec + (size_t)st * REC_B + (size_t)lane * 16;
        unsigned char* lb = sm + bufi * REC_B;
#pragma unroll
        for (int c = 0; c < 7; ++c) {
            const int q = c * 4 + w;
            GLDS16(gp + q * 1024, lb + q * 1024);
        }
    };

    for (int it = 0; it < 3; ++it) {
        // ---------------- pass ----------------
        issue(bid, 0);
        if (bid + G < NUNIT) issue(bid + G, 1);
        __syncthreads();                 // vmcnt(0) drain: buffers resident

        float* red = (float*)sm;         // [64][164] f32 alias for block reduce

        if (it == 0) {
            // uniform c: dense MFMA accumulate (2 i per MFMA along K)
            f32x16 acc[5];
#pragma unroll
            for (int op = 0; op < 5; ++op)
#pragma unroll
                for (int k = 0; k < 16; ++k) acc[op][k] = 0.f;

            int cur = 0;
            for (int st = bid; st < NUNIT; st += G) {
                const unsigned char* buf = sm + cur * REC_B;
#pragma unroll
                for (int ip = 0; ip < 2; ++ip) {
                    const int il0 = ph * 4 + ip * 2;
                    half8 xb = *(const half8*)(buf + XOFF_B + (il0 + hi) * 1024 + b * 16);
#pragma unroll
                    for (int op = 0; op < 5; ++op) {
                        half8 av = *(const half8*)(buf + (il0 + hi) * 2560 + op * 512 + lo * 16);
                        acc[op] = __builtin_amdgcn_mfma_f32_32x32x16_f16(av, xb, acc[op], 0, 0, 0);
                    }
                }
                const int nxt = st + 2 * G;
                if (nxt < NUNIT) { __syncthreads(); issue(nxt, cur); __syncthreads(); }
                cur ^= 1;
            }
#pragma unroll 1
            for (int phase = 0; phase < 2; ++phase) {
                __syncthreads();
                if (ph == phase) {
#pragma unroll
                    for (int op = 0; op < 5; ++op)
#pragma unroll
                        for (int q = 0; q < 8; ++q) {
                            const int o  = op * 2 + (q >> 2);
                            const int d0 = 2 * (q & 1) + 8 * ((q >> 1) & 1) + 4 * hi;
                            float e0 = acc[op][2 * q], e1 = acc[op][2 * q + 1];
                            float* p = &red[(size_t)b * 164 + o * 16 + d0];
                            if (phase == 0) *(float2*)p = make_float2(e0, e1);
                            else { float2 v2 = *(const float2*)p; v2.x += e0; v2.y += e1; *(float2*)p = v2; }
                        }
                }
            }
        } else {
            // routing pass (round-5 verified math)
            h2 vh[10][4];
            {
                const float* vp = Vacc + (size_t)b * (OC * 16);
                const float L2E = 1.44269504f;
#pragma unroll
                for (int o = 0; o < OC; ++o) {
                    float4 fa = *(const float4*)(vp + o * 16 + 4 * hi);
                    float4 fb = *(const float4*)(vp + o * 16 + 8 + 4 * hi);
                    vh[o][0] = asb(pk_rn(fa.x * L2E, fa.y * L2E));
                    vh[o][1] = asb(pk_rn(fa.z * L2E, fa.w * L2E));
                    vh[o][2] = asb(pk_rn(fb.x * L2E, fb.y * L2E));
                    vh[o][3] = asb(pk_rn(fb.z * L2E, fb.w * L2E));
                }
            }
            h2 acch[5][8];
#pragma unroll
            for (int op = 0; op < 5; ++op)
#pragma unroll
                for (int q = 0; q < 8; ++q) acch[op][q] = h2{(__fp16)0.f, (__fp16)0.f};
            f32x16 zc;
#pragma unroll
            for (int k = 0; k < 16; ++k) zc[k] = 0.f;

            int cur = 0;
            for (int st = bid; st < NUNIT; st += G) {
                const unsigned char* buf = sm + cur * REC_B;
#pragma unroll 1
                for (int u = 0; u < 4; ++u) {
                    const int il = ph * 4 + u;
                    const unsigned char* xaddr = (lane < 32)
                        ? (buf + XOFF_B + il * 1024 + b * 16)
                        : (const unsigned char*)zs;
                    half8 xb = *(const half8*)xaddr;

                    h2 uh2[5][8];
                    float lgf[10];
#pragma unroll
                    for (int op = 0; op < 5; ++op) {
                        half8 av = *(const half8*)(buf + il * 2560 + op * 512 + lo * 16);
                        f32x16 C = __builtin_amdgcn_mfma_f32_32x32x16_f16(av, xb, zc, 0, 0, 0);
#pragma unroll
                        for (int q = 0; q < 8; ++q)
                            uh2[op][q] = __builtin_amdgcn_cvt_pkrtz(C[2 * q], C[2 * q + 1]);
                        float l0 = 0.f, l1 = 0.f;
#pragma unroll
                        for (int qq = 0; qq < 4; ++qq) {
                            l0 = dot2(uh2[op][qq],     vh[op * 2][qq],     l0);
                            l1 = dot2(uh2[op][4 + qq], vh[op * 2 + 1][qq], l1);
                        }
                        lgf[op * 2]     = l0;
                        lgf[op * 2 + 1] = l1;
                    }
#pragma unroll
                    for (int pp = 0; pp < 5; ++pp) {
                        h2 lp = asb(pk_rn(lgf[2 * pp], lgf[2 * pp + 1]));
                        int ob = __shfl_xor(__builtin_bit_cast(int, lp), 32);
                        h2 s2 = lp + __builtin_bit_cast(h2, ob);
                        lgf[2 * pp]     = (float)s2[0];
                        lgf[2 * pp + 1] = (float)s2[1];
                    }
                    float m0 = fmaxf(fmaxf(lgf[0], lgf[1]), lgf[2]);
                    float m1 = fmaxf(fmaxf(lgf[3], lgf[4]), lgf[5]);
                    float m2 = fmaxf(fmaxf(lgf[6], lgf[7]), lgf[8]);
                    float mx = fmaxf(fmaxf(m0, m1), fmaxf(m2, lgf[9]));
                    float pe[10];
#pragma unroll
                    for (int o = 0; o < OC; ++o)
                        pe[o] = __builtin_amdgcn_exp2f(lgf[o] - mx);
                    float s01 = pe[0] + pe[1], s23 = pe[2] + pe[3];
                    float s45 = pe[4] + pe[5], s67 = pe[6] + pe[7];
                    float s89 = pe[8] + pe[9];
                    float se = ((s01 + s23) + (s45 + s67)) + s89;
                    float rs = __builtin_amdgcn_rcpf(se);
#pragma unroll
                    for (int op = 0; op < 5; ++op) {
                        float c0 = pe[op * 2] * rs;
                        float c1 = pe[op * 2 + 1] * rs;
                        h2 ch0 = __builtin_amdgcn_cvt_pkrtz(c0, c0);
                        h2 ch1 = __builtin_amdgcn_cvt_pkrtz(c1, c1);
#pragma unroll
                        for (int q = 0; q < 4; ++q) {
                            acch[op][q]     = ch0 * uh2[op][q]     + acch[op][q];
                            acch[op][4 + q] = ch1 * uh2[op][4 + q] + acch[op][4 + q];
                        }
                    }
                }
                const int nxt = st + 2 * G;
                if (nxt < NUNIT) { __syncthreads(); issue(nxt, cur); __syncthreads(); }
                cur ^= 1;
            }
#pragma unroll 1
            for (int phase = 0; phase < 2; ++phase) {
                __syncthreads();
                if (ph == phase) {
#pragma unroll
                    for (int op = 0; op < 5; ++op)
#pragma unroll
                        for (int q = 0; q < 8; ++q) {
                            const int o  = op * 2 + (q >> 2);
                            const int d0 = 2 * (q & 1) + 8 * ((q >> 1) & 1) + 4 * hi;
                            float e0 = (float)acch[op][q][0], e1 = (float)acch[op][q][1];
                            float* p = &red[(size_t)b * 164 + o * 16 + d0];
                            if (phase == 0) *(float2*)p = make_float2(e0, e1);
                            else { float2 v2 = *(const float2*)p; v2.x += e0; v2.y += e1; *(float2*)p = v2; }
                        }
                }
            }
        }
        __syncthreads();
        // flush partial as f16, transposed: part[bo][chunk][16]
        unsigned int* dst = (unsigned int*)part;
        for (int q = t; q < PART_H / 2; q += 256) {
            int bo = q >> 3;
            int u8 = q & 7;
            int bb = bo / 10;
            int oo = bo - bb * 10;
            float2 v2 = *(const float2*)&red[(size_t)bb * 164 + oo * 16 + u8 * 2];
            dst[(size_t)(bo * G + bid) * 8 + u8] = pk_rn(v2.x, v2.y);
        }
        gg.sync();

        // ---------------- reduce ----------------
        const float scale = (it == 0) ? 0.1f : 1.0f;
        for (int bo = bid; bo < 640; bo += G) {
            __syncthreads();             // redsm safe to rewrite
            const unsigned int* p32 = (const unsigned int*)part + (size_t)bo * G * 8;
            float4 a = make_float4(0.f, 0.f, 0.f, 0.f);
            for (int c = s4; c < G; c += 64) {
                uint2 v = *(const uint2*)(p32 + (size_t)c * 8 + d2 * 2);
                h2 lov = asb(v.x), hiv = asb(v.y);
                a.x += (float)lov[0]; a.y += (float)lov[1];
                a.z += (float)hiv[0]; a.w += (float)hiv[1];
            }
#pragma unroll
            for (int m = 4; m <= 32; m <<= 1) {
                a.x += __shfl_xor(a.x, m); a.y += __shfl_xor(a.y, m);
                a.z += __shfl_xor(a.z, m); a.w += __shfl_xor(a.w, m);
            }
            if (lane < 4) {
                redsm[w][d2 * 4 + 0] = a.x; redsm[w][d2 * 4 + 1] = a.y;
                redsm[w][d2 * 4 + 2] = a.z; redsm[w][d2 * 4 + 3] = a.w;
            }
            __syncthreads();
            if (t < 16) {
                float sv = (redsm[0][t] + redsm[1][t] + redsm[2][t] + redsm[3][t]) * scale;
                float n2 = sv * sv;
#pragma unroll
                for (int m = 1; m < 16; m <<= 1) n2 += __shfl_xor(n2, m);
                float norm = sqrtf(n2);
                float scl  = n2 / (1.f + n2) / (norm + 1e-8f);
                float v = scl * sv;
                if (it == 2)      out[bo * 16 + t] = v;
                else if (it == 0) Vacc[bo * 16 + t] = v;
                else              Vacc[bo * 16 + t] += v;
            }
        }
        gg.sync();
    }
}

extern "C" void kernel_launch(void* const* d_in, const int* in_sizes, int n_in,
                              void* d_out, int out_size, void* d_ws, size_t ws_size,
                              hipStream_t stream) {
    const float* x = (const float*)d_in[0];   // (64, 8000, 8)
    const float* W = (const float*)d_in[1];   // (10, 8000, 16, 8)
    float* out = (float*)d_out;               // (64, 10, 16)

    char* ws = (char*)d_ws;
    float*  Vacc = (float*)ws;                                  // 40 KB
    __fp16* rec  = (__fp16*)(ws + VACC_F * sizeof(float));      // 28.7 MB f16 records
    __fp16* part = (__fp16*)(ws + VACC_F * sizeof(float) + REC_TOTAL_B);

    // co-residency-safe grid (cooperative launch must not oversubscribe)
    static int grid_cached = 0;
    if (grid_cached == 0) {
        int maxb = 0;
        if (hipOccupancyMaxActiveBlocksPerMultiprocessor(&maxb, caps_fused, 256, 0)
                != hipSuccess || maxb < 1)
            maxb = 1;
        long g = (long)maxb * 256;
        if (g > 512) g = 512;
        grid_cached = (int)g;
    }
    long grid = grid_cached;

    size_t head = VACC_F * sizeof(float) + REC_TOTAL_B;
    size_t avail = (ws_size > head) ? ws_size - head : 0;
    long slots = (long)(avail / (PART_H * sizeof(__fp16)));
    if (grid > slots) grid = slots;
    if (grid < 1) grid = 1;

    void* args[] = {(void*)&W, (void*)&x, (void*)&rec, (void*)&Vacc,
                    (void*)&part, (void*)&out};
    hipLaunchCooperativeKernel((const void*)caps_fused, dim3((unsigned)grid),
                               dim3(256), args, 0, stream);
}

// Round 7
// 168.202 us; speedup vs baseline: 2.2604x; 2.2604x over previous
//
#include <hip/hip_runtime.h>
#include <hip/hip_fp16.h>
#include <math.h>

#define IN 8000
#define OC 10
#define NUNIT 1000              // 1000 units x 8 i
#define VACC_F (64 * OC * 16)   // 10240 floats
#define PART_H (64 * OC * 16)   // 10240 halfs per chunk (20 KB)

// per-unit f16 record: [8 il][10 o][16 d][8 e] (20480 B) then [8 il][64 b][8 e] (8192 B)
#define REC_B   28672
#define REC_H   14336
#define XOFF_B  20480
#define XOFF_H  10240
#define REC_TOTAL_B ((size_t)NUNIT * REC_B)   // 28,672,000

typedef __fp16 h2 __attribute__((ext_vector_type(2)));
typedef _Float16 half8 __attribute__((ext_vector_type(8)));
typedef float f32x16 __attribute__((ext_vector_type(16)));

__device__ __forceinline__ h2 asb(unsigned int v) { return __builtin_bit_cast(h2, v); }

__device__ __forceinline__ float dot2(h2 a, h2 b, float c) {
#if __has_builtin(__builtin_amdgcn_fdot2)
    return __builtin_amdgcn_fdot2(a, b, c, false);
#else
    return fmaf((float)a[0], (float)b[0], fmaf((float)a[1], (float)b[1], c));
#endif
}

__device__ __forceinline__ unsigned int pk_rn(float a, float b) {
    return __builtin_bit_cast(unsigned int, __float22half2_rn(make_float2(a, b)));
}

#define GLDS16(gp, lp) __builtin_amdgcn_global_load_lds(                      \
    (const __attribute__((address_space(1))) void*)(gp),                      \
    (__attribute__((address_space(3))) void*)(lp), 16, 0, 0)

// ---------------------------------------------------------------------------
// Pass 0 (UNIFORM) + prep fused: per unit, stage W/x f32 -> f16 into LDS
// (round-1-verified pattern, LDS layout == rec record layout), run the
// dense MFMA accumulation (round-5-verified), then copy the LDS image
// linearly to rec for passes 1-2. Kills the standalone prep kernel and
// pass-0's rec read (~29 MB less traffic, one fewer launch).
// ---------------------------------------------------------------------------
__global__ __launch_bounds__(256, 2) void caps_pass0(
    const float* __restrict__ W, const float* __restrict__ x,
    __fp16* __restrict__ rec, __fp16* __restrict__ part)
{
    // 41984 B: staging image occupies [0, 28672); epilogue red-alias needs all
    __shared__ __align__(16) unsigned char sm[41984];

    const int t    = threadIdx.x;
    const int w    = t >> 6;
    const int lane = t & 63;
    const int lo   = lane & 31;
    const int hi   = lane >> 5;
    const int bt   = w & 1;            // b-half
    const int ph   = w >> 1;           // i-set half
    const int b    = bt * 32 + lo;
    const int bid  = blockIdx.x;
    const int grid = gridDim.x;

    unsigned short* Wl = (unsigned short*)sm;              // [8 il][10 o][128 h]
    unsigned short* xl = (unsigned short*)(sm + XOFF_B);   // [8 il][64 b][8 h]

    f32x16 acc[5];
#pragma unroll
    for (int op = 0; op < 5; ++op)
#pragma unroll
        for (int k = 0; k < 16; ++k) acc[op][k] = 0.f;

    for (int st = bid; st < NUNIT; st += grid) {
        const int is = st * 8;
        __syncthreads();               // prev unit's LDS readers done
        // stage W: 8*320 float4 -> f16 (10 iters/thread)
        for (int j = t; j < 8 * 320; j += 256) {
            int il = j >> 5;           // wait: 320 per il -> use div
            il = j / 320;
            int r  = j - il * 320;
            int o  = r >> 5;
            int f  = r & 31;
            float4 w4 = *(const float4*)(W + (size_t)o * (IN * 128) +
                                         (size_t)(is + il) * 128 + f * 4);
            *(uint2*)&Wl[il * 1280 + o * 128 + f * 4] =
                make_uint2(pk_rn(w4.x, w4.y), pk_rn(w4.z, w4.w));
        }
        // stage x: 8*128 float4 -> f16 (4 iters/thread)
        for (int j = t; j < 8 * 128; j += 256) {
            int bb = j >> 4;
            int r  = j & 15;
            int il = r >> 1;
            int hh = r & 1;
            float4 x4 = *(const float4*)(x + (size_t)bb * (IN * 8) +
                                         (size_t)(is + il) * 8 + hh * 4);
            *(uint2*)&xl[il * 512 + bb * 8 + hh * 4] =
                make_uint2(pk_rn(x4.x, x4.y), pk_rn(x4.z, x4.w));
        }
        __syncthreads();               // staged image resident

        // copy-out LDS image -> rec (1792 uint4, 7/thread, coalesced;
        // stores are fire-and-forget)
        {
            const uint4* srcv = (const uint4*)sm;
            uint4* dstv = (uint4*)((char*)rec + (size_t)st * REC_B);
#pragma unroll
            for (int c = 0; c < 7; ++c) dstv[c * 256 + t] = srcv[c * 256 + t];
        }

        // dense MFMA: 2 i per MFMA along K (k-group = lane>>5 -> i')
#pragma unroll
        for (int ip = 0; ip < 2; ++ip) {
            const int il0 = ph * 4 + ip * 2;
            half8 xb = *(const half8*)(sm + XOFF_B + (il0 + hi) * 1024 + b * 16);
#pragma unroll
            for (int op = 0; op < 5; ++op) {
                half8 av = *(const half8*)(sm + (il0 + hi) * 2560 + op * 512 + lo * 16);
                acc[op] = __builtin_amdgcn_mfma_f32_32x32x16_f16(av, xb, acc[op], 0, 0, 0);
            }
        }
    }

    // block reduce across the two ph-waves per bt; red aliases sm: [64][164] f32
    float* red = (float*)sm;
#pragma unroll 1
    for (int phase = 0; phase < 2; ++phase) {
        __syncthreads();
        if (ph == phase) {
#pragma unroll
            for (int op = 0; op < 5; ++op)
#pragma unroll
                for (int q = 0; q < 8; ++q) {
                    const int o  = op * 2 + (q >> 2);
                    const int d0 = 2 * (q & 1) + 8 * ((q >> 1) & 1) + 4 * hi;
                    float e0 = acc[op][2 * q], e1 = acc[op][2 * q + 1];
                    float* p = &red[(size_t)b * 164 + o * 16 + d0];
                    if (phase == 0) *(float2*)p = make_float2(e0, e1);
                    else { float2 v2 = *(const float2*)p; v2.x += e0; v2.y += e1; *(float2*)p = v2; }
                }
        }
    }
    __syncthreads();
    // flush partial as f16, transposed: part[bo][chunk][16]
    unsigned int* dst = (unsigned int*)part;
    for (int q = t; q < PART_H / 2; q += 256) {
        int bo = q >> 3;
        int u8 = q & 7;
        int bb = bo / 10;
        int oo = bo - bb * 10;
        float2 v2 = *(const float2*)&red[(size_t)bb * 164 + oo * 16 + u8 * 2];
        dst[(size_t)(bo * grid + bid) * 8 + u8] = pk_rn(v2.x, v2.y);
    }
}

// ---------------------------------------------------------------------------
// Routing pass (round-5 verified, verbatim): 256 thr, grid = 500, 2 units
// per block DMA'd up-front via global_load_lds; one drain barrier; packed-
// f16 accumulator, max3 softmax, tree exp-sum.
// ---------------------------------------------------------------------------
__global__ __launch_bounds__(256, 2) void caps_pass(
    const __fp16* __restrict__ rec, const float* __restrict__ Vacc,
    __fp16* __restrict__ part)
{
    __shared__ __align__(16) unsigned char sm[2 * REC_B];   // 57344 B
    __shared__ __align__(16) unsigned char zs[16];          // zero slot

    const int t    = threadIdx.x;
    const int w    = t >> 6;
    const int lane = t & 63;
    const int lo   = lane & 31;
    const int hi   = lane >> 5;
    const int bt   = w & 1;
    const int ph   = w >> 1;
    const int b    = bt * 32 + lo;

    if (t < 4) ((unsigned int*)zs)[t] = 0u;

    h2 vh[10][4];
    {
        const float* vp = Vacc + (size_t)b * (OC * 16);
        const float L2E = 1.44269504f;
#pragma unroll
        for (int o = 0; o < OC; ++o) {
            float4 fa = *(const float4*)(vp + o * 16 + 4 * hi);
            float4 fb = *(const float4*)(vp + o * 16 + 8 + 4 * hi);
            vh[o][0] = asb(pk_rn(fa.x * L2E, fa.y * L2E));
            vh[o][1] = asb(pk_rn(fa.z * L2E, fa.w * L2E));
            vh[o][2] = asb(pk_rn(fb.x * L2E, fb.y * L2E));
            vh[o][3] = asb(pk_rn(fb.z * L2E, fb.w * L2E));
        }
    }

    h2 acch[5][8];
#pragma unroll
    for (int op = 0; op < 5; ++op)
#pragma unroll
        for (int q = 0; q < 8; ++q) acch[op][q] = h2{(__fp16)0.f, (__fp16)0.f};

    f32x16 zc;
#pragma unroll
    for (int k = 0; k < 16; ++k) zc[k] = 0.f;

    const int bid  = blockIdx.x;
    const int grid = gridDim.x;

    auto issue = [&](int st, int bufi) {
        const char* g = (const char*)rec + (size_t)st * REC_B + (size_t)lane * 16;
        unsigned char* lb = sm + bufi * REC_B;
#pragma unroll
        for (int c = 0; c < 7; ++c) {
            const int q = c * 4 + w;
            GLDS16(g + q * 1024, lb + q * 1024);
        }
    };

    issue(bid, 0);
    if (bid + grid < NUNIT) issue(bid + grid, 1);
    __syncthreads();                 // drains vmcnt(0): both buffers resident

    int cur = 0;
    for (int st = bid; st < NUNIT; st += grid) {
        const unsigned char* buf = sm + cur * REC_B;

#pragma unroll 1
        for (int u = 0; u < 4; ++u) {
            const int il = ph * 4 + u;
            const unsigned char* xaddr = (lane < 32)
                ? (buf + XOFF_B + il * 1024 + b * 16)
                : (const unsigned char*)zs;
            half8 xb = *(const half8*)xaddr;

            h2 uh2[5][8];
            float lgf[10];
#pragma unroll
            for (int op = 0; op < 5; ++op) {
                half8 av = *(const half8*)(buf + il * 2560 + op * 512 + lo * 16);
                f32x16 C = __builtin_amdgcn_mfma_f32_32x32x16_f16(av, xb, zc, 0, 0, 0);
#pragma unroll
                for (int q = 0; q < 8; ++q)
                    uh2[op][q] = __builtin_amdgcn_cvt_pkrtz(C[2 * q], C[2 * q + 1]);
                float l0 = 0.f, l1 = 0.f;
#pragma unroll
                for (int qq = 0; qq < 4; ++qq) {
                    l0 = dot2(uh2[op][qq],     vh[op * 2][qq],     l0);
                    l1 = dot2(uh2[op][4 + qq], vh[op * 2 + 1][qq], l1);
                }
                lgf[op * 2]     = l0;
                lgf[op * 2 + 1] = l1;
            }
#pragma unroll
            for (int pp = 0; pp < 5; ++pp) {
                h2 lp = asb(pk_rn(lgf[2 * pp], lgf[2 * pp + 1]));
                int ob = __shfl_xor(__builtin_bit_cast(int, lp), 32);
                h2 s2 = lp + __builtin_bit_cast(h2, ob);
                lgf[2 * pp]     = (float)s2[0];
                lgf[2 * pp + 1] = (float)s2[1];
            }
            float m0 = fmaxf(fmaxf(lgf[0], lgf[1]), lgf[2]);
            float m1 = fmaxf(fmaxf(lgf[3], lgf[4]), lgf[5]);
            float m2 = fmaxf(fmaxf(lgf[6], lgf[7]), lgf[8]);
            float mx = fmaxf(fmaxf(m0, m1), fmaxf(m2, lgf[9]));
            float pe[10];
#pragma unroll
            for (int o = 0; o < OC; ++o)
                pe[o] = __builtin_amdgcn_exp2f(lgf[o] - mx);
            float s01 = pe[0] + pe[1], s23 = pe[2] + pe[3];
            float s45 = pe[4] + pe[5], s67 = pe[6] + pe[7];
            float s89 = pe[8] + pe[9];
            float se = ((s01 + s23) + (s45 + s67)) + s89;
            float rs = __builtin_amdgcn_rcpf(se);
#pragma unroll
            for (int op = 0; op < 5; ++op) {
                float c0 = pe[op * 2] * rs;
                float c1 = pe[op * 2 + 1] * rs;
                h2 ch0 = __builtin_amdgcn_cvt_pkrtz(c0, c0);
                h2 ch1 = __builtin_amdgcn_cvt_pkrtz(c1, c1);
#pragma unroll
                for (int q = 0; q < 4; ++q) {
                    acch[op][q]     = ch0 * uh2[op][q]     + acch[op][q];
                    acch[op][4 + q] = ch1 * uh2[op][4 + q] + acch[op][4 + q];
                }
            }
        }

        const int nxt = st + 2 * grid;
        if (nxt < NUNIT) {
            __syncthreads();
            issue(nxt, cur);
            __syncthreads();
        }
        cur ^= 1;
    }

    float* red = (float*)sm;
#pragma unroll 1
    for (int phase = 0; phase < 2; ++phase) {
        __syncthreads();
        if (ph == phase) {
#pragma unroll
            for (int op = 0; op < 5; ++op)
#pragma unroll
                for (int q = 0; q < 8; ++q) {
                    const int o  = op * 2 + (q >> 2);
                    const int d0 = 2 * (q & 1) + 8 * ((q >> 1) & 1) + 4 * hi;
                    float e0 = (float)acch[op][q][0], e1 = (float)acch[op][q][1];
                    float* p = &red[(size_t)b * 164 + o * 16 + d0];
                    if (phase == 0) *(float2*)p = make_float2(e0, e1);
                    else { float2 v2 = *(const float2*)p; v2.x += e0; v2.y += e1; *(float2*)p = v2; }
                }
        }
    }
    __syncthreads();
    unsigned int* dst = (unsigned int*)part;
    for (int q = t; q < PART_H / 2; q += 256) {
        int bo = q >> 3;
        int u8 = q & 7;
        int bb = bo / 10;
        int oo = bo - bb * 10;
        float2 v2 = *(const float2*)&red[(size_t)bb * 164 + oo * 16 + u8 * 2];
        dst[(size_t)(bo * grid + bid) * 8 + u8] = pk_rn(v2.x, v2.y);
    }
}

// ---------------------------------------------------------------------------
// Kernel B: one block per (b,o). part is [bo][chunk][16] f16 -> coalesced.
// mode 0: Vacc =, mode 1: Vacc +=, mode 2: out =.
// ---------------------------------------------------------------------------
__global__ __launch_bounds__(256) void caps_reduce(
    const __fp16* __restrict__ part, float* __restrict__ Vacc,
    float* __restrict__ out, int nchunk, int mode, float scale)
{
    const int bo = blockIdx.x;      // b*10+o, [0,640)
    const int t  = threadIdx.x;
    const int d2 = t & 3;
    const int s  = t >> 2;

    const unsigned int* p32 = (const unsigned int*)part + (size_t)bo * nchunk * 8;
    float4 a = make_float4(0.f, 0.f, 0.f, 0.f);
    for (int c = s; c < nchunk; c += 64) {
        uint2 v = *(const uint2*)(p32 + (size_t)c * 8 + d2 * 2);
        h2 lov = asb(v.x), hiv = asb(v.y);
        a.x += (float)lov[0]; a.y += (float)lov[1];
        a.z += (float)hiv[0]; a.w += (float)hiv[1];
    }
#pragma unroll
    for (int m = 4; m <= 32; m <<= 1) {
        a.x += __shfl_xor(a.x, m); a.y += __shfl_xor(a.y, m);
        a.z += __shfl_xor(a.z, m); a.w += __shfl_xor(a.w, m);
    }
    __shared__ float red[4][16];
    const int wv = t >> 6;
    if ((t & 63) < 4) {
        red[wv][d2 * 4 + 0] = a.x; red[wv][d2 * 4 + 1] = a.y;
        red[wv][d2 * 4 + 2] = a.z; red[wv][d2 * 4 + 3] = a.w;
    }
    __syncthreads();
    if (t < 16) {
        float sv = (red[0][t] + red[1][t] + red[2][t] + red[3][t]) * scale;
        float n2 = sv * sv;
#pragma unroll
        for (int m = 1; m < 16; m <<= 1) n2 += __shfl_xor(n2, m);
        float norm = sqrtf(n2);
        float scl  = n2 / (1.f + n2) / (norm + 1e-8f);
        float v = scl * sv;
        if (mode == 2)      out[bo * 16 + t] = v;
        else if (mode == 0) Vacc[bo * 16 + t] = v;
        else                Vacc[bo * 16 + t] += v;
    }
}

extern "C" void kernel_launch(void* const* d_in, const int* in_sizes, int n_in,
                              void* d_out, int out_size, void* d_ws, size_t ws_size,
                              hipStream_t stream) {
    const float* x = (const float*)d_in[0];   // (64, 8000, 8)
    const float* W = (const float*)d_in[1];   // (10, 8000, 16, 8)
    float* out = (float*)d_out;               // (64, 10, 16)

    char* ws = (char*)d_ws;
    float*  Vacc = (float*)ws;                                  // 40 KB
    __fp16* rec  = (__fp16*)(ws + VACC_F * sizeof(float));      // 28.7 MB f16 records
    __fp16* part = (__fp16*)(ws + VACC_F * sizeof(float) + REC_TOTAL_B);

    size_t head = VACC_F * sizeof(float) + REC_TOTAL_B;
    size_t avail = (ws_size > head) ? ws_size - head : 0;
    long slots = (long)(avail / (PART_H * sizeof(__fp16)));
    int grid = (int)((slots < 500) ? slots : 500);
    if (grid < 1) grid = 1;

    // iter 0: prep fused into the uniform pass (c=0.1 folded into reduce scale)
    caps_pass0<<<grid, 256, 0, stream>>>(W, x, rec, part);
    caps_reduce<<<640, 256, 0, stream>>>(part, Vacc, out, grid, 0, 0.1f);
    // iter 1
    caps_pass<<<grid, 256, 0, stream>>>(rec, Vacc, part);
    caps_reduce<<<640, 256, 0, stream>>>(part, Vacc, out, grid, 1, 1.0f);
    // iter 2 (final): write v to out
    caps_pass<<<grid, 256, 0, stream>>>(rec, Vacc, part);
    caps_reduce<<<640, 256, 0, stream>>>(part, Vacc, out, grid, 2, 1.0f);
}